// Round 3
// baseline (82.014 us; speedup 1.0000x reference)
//
#include <hip/hip_runtime.h>
#include <math.h>

// Problem constants
#define B_  32
#define C_  256
#define H_  56
#define W_  56
#define CR_ 64          // C/RED
#define HW_ (H_*W_)     // 3136
#define BC_ (B_*C_)     // 8192

// ---------------------------------------------------------------------------
// Kernel 1: global average pool. One block per (b,c) plane. HBM-read bound.
// ---------------------------------------------------------------------------
__global__ __launch_bounds__(256) void gap_kernel(const float* __restrict__ x,
                                                  float* __restrict__ gap) {
    const int bc = blockIdx.x;
    const float4* p4 = (const float4*)(x + (size_t)bc * HW_);
    float s = 0.f;
    for (int i = threadIdx.x; i < HW_ / 4; i += 256) {
        float4 v = p4[i];
        s += (v.x + v.y) + (v.z + v.w);
    }
    for (int off = 32; off > 0; off >>= 1) s += __shfl_down(s, off, 64);
    __shared__ float ws[4];
    const int lane = threadIdx.x & 63, wid = threadIdx.x >> 6;
    if (lane == 0) ws[wid] = s;
    __syncthreads();
    if (threadIdx.x == 0) {
        float t = (ws[0] + ws[1]) + (ws[2] + ws[3]);
        gap[bc] = t * (1.0f / (float)HW_);
    }
}

// ---------------------------------------------------------------------------
// Kernel 2a: hid = gelu(gap @ w1^T + b1). One block (64 threads) per batch.
// ---------------------------------------------------------------------------
__global__ __launch_bounds__(64) void hid_kernel(const float* __restrict__ gap,
                                                 const float* __restrict__ w1,
                                                 const float* __restrict__ b1,
                                                 float* __restrict__ hid_g) {
    const int b = blockIdx.x;
    __shared__ float g[C_];
    const int t = threadIdx.x;
    g[t] = gap[b * C_ + t];
    g[t + 64] = gap[b * C_ + t + 64];
    g[t + 128] = gap[b * C_ + t + 128];
    g[t + 192] = gap[b * C_ + t + 192];
    __syncthreads();
    float acc = b1[t];
    const float4* wr = (const float4*)(w1 + (size_t)t * C_);
    #pragma unroll 8
    for (int q = 0; q < C_ / 4; ++q) {
        float4 w = wr[q];
        acc += w.x * g[4*q] + w.y * g[4*q+1] + w.z * g[4*q+2] + w.w * g[4*q+3];
    }
    hid_g[b * CR_ + t] = 0.5f * acc * (1.0f + erff(acc * 0.7071067811865476f));
}

// ---------------------------------------------------------------------------
// Kernel 2b: logits + softmax. Grid 32 batches x 8 channel-slices (32 ch).
// w2 slice (288 rows x 64) staged coalesced into LDS at stride-66 floats
// (lane bank stride 18 -> 2-way aliasing = free). 320 threads, 288 active.
// ---------------------------------------------------------------------------
#define W2STRIDE 66
__global__ __launch_bounds__(320) void logits_kernel(const float* __restrict__ hid_g,
                                                     const float* __restrict__ w2,
                                                     const float* __restrict__ b2,
                                                     float* __restrict__ wk) {
    const int b  = blockIdx.x >> 3;
    const int c0 = (blockIdx.x & 7) * 32;
    __shared__ float w2s[288 * W2STRIDE];
    __shared__ float hs[CR_];
    __shared__ float lgs[288];

    const int tid = threadIdx.x;
    if (tid < CR_) hs[tid] = hid_g[b * CR_ + tid];

    // stage 288 rows x 32 float2, coalesced from global
    const float2* src2 = (const float2*)(w2 + (size_t)c0 * 9 * CR_);
    float2* dst2 = (float2*)w2s;
    for (int i = tid; i < 288 * 32; i += 320) {
        const int row = i >> 5, q = i & 31;
        dst2[row * (W2STRIDE / 2) + q] = src2[row * 32 + q];
    }
    __syncthreads();

    if (tid < 288) {
        const int c_local = tid & 31, t = tid >> 5;   // t in 0..8
        const int row = c_local * 9 + t;
        float acc = b2[(c0 + c_local) * 9 + t];
        const float* wr = w2s + row * W2STRIDE;
        #pragma unroll 16
        for (int k = 0; k < CR_; ++k) acc += wr[k] * hs[k];
        lgs[row] = acc;
    }
    __syncthreads();

    if (tid < 32) {
        const float* l = lgs + tid * 9;
        float mx = -INFINITY;
        #pragma unroll
        for (int t = 0; t < 9; ++t) mx = fmaxf(mx, l[t]);
        float e[9], den = 0.f;
        #pragma unroll
        for (int t = 0; t < 9; ++t) { e[t] = expf(l[t] - mx); den += e[t]; }
        const float inv = 1.0f / den;
        float* o = wk + ((size_t)b * C_ + c0 + tid) * 9;
        #pragma unroll
        for (int t = 0; t < 9; ++t) o[t] = e[t] * inv;
    }
}

// ---------------------------------------------------------------------------
// Kernel 3: dynamic 3x3 depthwise conv + residual.
// 2 blocks per plane (28 output rows each). LDS: 30 rows x 64 cols, zero halo
// (rows clipped; cols 3 and 60 are zero). Each thread: 4 output cols via
// ds_read_b128 + b64(left) + b32(right), pure-FMA VALU, float4 stores.
// ---------------------------------------------------------------------------
__global__ __launch_bounds__(256) void dconv_kernel(const float* __restrict__ x,
                                                    const float* __restrict__ wk,
                                                    float* __restrict__ out) {
    const int bc = blockIdx.x >> 1;
    const int h  = blockIdx.x & 1;
    const int gy0 = h * 28 - 1;                  // global row of LDS row 0
    const float* p = x + (size_t)bc * HW_;
    float* o = out + (size_t)bc * HW_;

    __shared__ float sm[30 * 64];
    __shared__ float kw[9];
    float4* sm4 = (float4*)sm;

    const int tid = threadIdx.x;
    for (int i = tid; i < 30 * 16; i += 256)
        sm4[i] = make_float4(0.f, 0.f, 0.f, 0.f);
    if (tid < 9) kw[tid] = wk[(size_t)bc * 9 + tid];
    __syncthreads();

    const float4* p4 = (const float4*)p;
    for (int i = tid; i < 30 * 14; i += 256) {
        const int r = i / 14, q = i - r * 14;
        const int gr = gy0 + r;
        if ((unsigned)gr < 56u) sm4[r * 16 + 1 + q] = p4[gr * 14 + q];
    }
    __syncthreads();

    const float k0 = kw[0], k1 = kw[1], k2 = kw[2];
    const float k3 = kw[3], k4 = kw[4], k5 = kw[5];
    const float k6 = kw[6], k7 = kw[7], k8 = kw[8];

    const int g  = tid & 15;                     // col group: cols 4g..4g+3
    const int rb = tid >> 4;                     // 0..15
    const int cg = (g < 14) ? g : 13;            // clamp to stay in-bounds

    #pragma unroll
    for (int pass = 0; pass < 2; ++pass) {
        const int yl = rb + pass * 16;           // local output row 0..27
        if (yl < 28) {
            const float* base = sm + yl * 64 + 4 * cg;
            // row y-1 (LDS row yl)
            const float4 A  = *(const float4*)(base + 4);
            const float  La = ((const float2*)(base + 2))[0].y;
            const float  Ra = base[8];
            // row y (LDS row yl+1)
            const float4 Bv = *(const float4*)(base + 64 + 4);
            const float  Lb = ((const float2*)(base + 64 + 2))[0].y;
            const float  Rb = base[64 + 8];
            // row y+1 (LDS row yl+2)
            const float4 Cv = *(const float4*)(base + 128 + 4);
            const float  Lc = ((const float2*)(base + 128 + 2))[0].y;
            const float  Rc = base[128 + 8];

            float o0 = La  * k0 + A.x * k1 + A.y * k2
                     + Lb  * k3 + Bv.x * k4 + Bv.y * k5
                     + Lc  * k6 + Cv.x * k7 + Cv.y * k8 + Bv.x;
            float o1 = A.x * k0 + A.y * k1 + A.z * k2
                     + Bv.x * k3 + Bv.y * k4 + Bv.z * k5
                     + Cv.x * k6 + Cv.y * k7 + Cv.z * k8 + Bv.y;
            float o2 = A.y * k0 + A.z * k1 + A.w * k2
                     + Bv.y * k3 + Bv.z * k4 + Bv.w * k5
                     + Cv.y * k6 + Cv.z * k7 + Cv.w * k8 + Bv.z;
            float o3 = A.z * k0 + A.w * k1 + Ra * k2
                     + Bv.z * k3 + Bv.w * k4 + Rb * k5
                     + Cv.z * k6 + Cv.w * k7 + Rc * k8 + Bv.w;

            if (g < 14) {
                const int y = h * 28 + yl;
                *(float4*)(o + y * W_ + 4 * g) = make_float4(o0, o1, o2, o3);
            }
        }
    }
}

// ---------------------------------------------------------------------------
extern "C" void kernel_launch(void* const* d_in, const int* in_sizes, int n_in,
                              void* d_out, int out_size, void* d_ws, size_t ws_size,
                              hipStream_t stream) {
    const float* x  = (const float*)d_in[0];
    const float* w1 = (const float*)d_in[1];
    const float* b1 = (const float*)d_in[2];
    const float* w2 = (const float*)d_in[3];
    const float* b2 = (const float*)d_in[4];
    float* out = (float*)d_out;

    float* gap   = (float*)d_ws;                 // 8192 floats
    float* hid_g = gap + BC_;                    // 32*64 = 2048 floats
    float* wk    = hid_g + B_ * CR_;             // 32*2304 floats

    gap_kernel<<<BC_, 256, 0, stream>>>(x, gap);
    hid_kernel<<<B_, 64, 0, stream>>>(gap, w1, b1, hid_g);
    logits_kernel<<<B_ * 8, 320, 0, stream>>>(hid_g, w2, b2, wk);
    dconv_kernel<<<BC_ * 2, 256, 0, stream>>>(x, wk, out);
}

// Round 4
// 61.304 us; speedup vs baseline: 1.3378x; 1.3378x over previous
//
#include <hip/hip_runtime.h>
#include <math.h>

// Problem constants
#define B_  32
#define C_  256
#define H_  56
#define W_  56
#define CR_ 64          // C/RED
#define HW_ (H_*W_)     // 3136
#define BC_ (B_*C_)     // 8192

// ---------------------------------------------------------------------------
// Kernel 1: global average pool. One block per (b,c) plane. HBM-read bound.
// ---------------------------------------------------------------------------
__global__ __launch_bounds__(256) void gap_kernel(const float* __restrict__ x,
                                                  float* __restrict__ gap) {
    const int bc = blockIdx.x;
    const float4* p4 = (const float4*)(x + (size_t)bc * HW_);
    float s = 0.f;
    for (int i = threadIdx.x; i < HW_ / 4; i += 256) {
        float4 v = p4[i];
        s += (v.x + v.y) + (v.z + v.w);
    }
    for (int off = 32; off > 0; off >>= 1) s += __shfl_down(s, off, 64);
    __shared__ float ws[4];
    const int lane = threadIdx.x & 63, wid = threadIdx.x >> 6;
    if (lane == 0) ws[wid] = s;
    __syncthreads();
    if (threadIdx.x == 0) {
        float t = (ws[0] + ws[1]) + (ws[2] + ws[3]);
        gap[bc] = t * (1.0f / (float)HW_);
    }
}

// ---------------------------------------------------------------------------
// Kernel 2: hid = gelu(gap @ w1^T + b1). One block (256 thr) per batch;
// 4 lanes cooperate per output channel (16 float4 each + shfl reduce).
// ---------------------------------------------------------------------------
__global__ __launch_bounds__(256) void hid_kernel(const float* __restrict__ gap,
                                                  const float* __restrict__ w1,
                                                  const float* __restrict__ b1,
                                                  float* __restrict__ hid_g) {
    const int b = blockIdx.x;
    const int j = threadIdx.x >> 2;      // output channel 0..63
    const int part = threadIdx.x & 3;    // quarter 0..3
    const float4* wr = (const float4*)(w1 + (size_t)j * C_) + part * 16;
    const float4* gv = (const float4*)(gap + (size_t)b * C_) + part * 16;
    float acc = 0.f;
    #pragma unroll
    for (int q = 0; q < 16; ++q) {
        float4 w = wr[q], g = gv[q];
        acc += w.x * g.x + w.y * g.y + w.z * g.z + w.w * g.w;
    }
    acc += __shfl_xor(acc, 1, 64);
    acc += __shfl_xor(acc, 2, 64);
    if (part == 0) {
        acc += b1[j];
        hid_g[b * CR_ + j] = 0.5f * acc * (1.0f + erff(acc * 0.7071067811865476f));
    }
}

// ---------------------------------------------------------------------------
// Kernel 3: fused logits + softmax + dynamic 3x3 depthwise conv + residual.
// One block per (b,c) plane. LDS 58x64 (halo-only zero-fill, disjoint from
// interior staging -> ONE barrier). Lanes 0..8 compute this channel's 9
// logits from L2-hot hid/w2 while the block stages x. After the barrier each
// thread computes the 9 softmax weights redundantly (9 LDS broadcasts +
// 9 __expf) and runs the rolling-register conv (3 new ds_read_b32 per row).
// ---------------------------------------------------------------------------
__global__ __launch_bounds__(256) void dconv_kernel(const float* __restrict__ x,
                                                    const float* __restrict__ hid_g,
                                                    const float* __restrict__ w2,
                                                    const float* __restrict__ b2,
                                                    float* __restrict__ out) {
    const int bc = blockIdx.x;
    const int b  = bc >> 8;
    const int c  = bc & 255;
    const float* p = x + (size_t)bc * HW_;
    float* o = out + (size_t)bc * HW_;

    // LDS rows 0..57 = image rows -1..56; image col x -> LDS col x+4.
    // Read cols are 3..60; halo = rows {0,57} cols 3..60, cols {3,60} rows 1..56.
    __shared__ float sm[58 * 64];
    __shared__ float lgs[9];
    float4* sm4 = (float4*)sm;

    const int tid = threadIdx.x;

    // halo-only zero fill (228 cells, disjoint from interior)
    if (tid < 116) {
        const int r = (tid & 1) ? 57 : 0;
        sm[r * 64 + 3 + (tid >> 1)] = 0.f;
    } else if (tid < 228) {
        const int i = tid - 116;
        sm[(1 + (i >> 1)) * 64 + ((i & 1) ? 60 : 3)] = 0.f;
    }

    // logits for this channel (lanes 0..8), overlapped with staging
    if (tid < 9) {
        const float4* wr = (const float4*)(w2 + ((size_t)c * 9 + tid) * CR_);
        const float4* hv = (const float4*)(hid_g + (size_t)b * CR_);
        float acc = b2[c * 9 + tid];
        #pragma unroll
        for (int q = 0; q < 16; ++q) {
            float4 w = wr[q], h = hv[q];
            acc += w.x * h.x + w.y * h.y + w.z * h.z + w.w * h.w;
        }
        lgs[tid] = acc;
    }

    // interior stage: rows 1..56, cols 4..59 (float4), coalesced
    const float4* p4 = (const float4*)p;
    for (int i = tid; i < HW_ / 4; i += 256) {
        const int y = i / 14, q = i - y * 14;
        sm4[(y + 1) * 16 + 1 + q] = p4[i];
    }
    __syncthreads();

    // redundant per-thread softmax over the 9 taps (LDS broadcasts)
    float l0 = lgs[0], l1 = lgs[1], l2 = lgs[2], l3 = lgs[3], l4 = lgs[4],
          l5 = lgs[5], l6 = lgs[6], l7 = lgs[7], l8 = lgs[8];
    float mx = fmaxf(fmaxf(fmaxf(fmaxf(l0, l1), fmaxf(l2, l3)),
                           fmaxf(fmaxf(l4, l5), fmaxf(l6, l7))), l8);
    float k0 = __expf(l0 - mx), k1 = __expf(l1 - mx), k2 = __expf(l2 - mx),
          k3 = __expf(l3 - mx), k4 = __expf(l4 - mx), k5 = __expf(l5 - mx),
          k6 = __expf(l6 - mx), k7 = __expf(l7 - mx), k8 = __expf(l8 - mx);
    const float inv = 1.0f / (((k0 + k1) + (k2 + k3)) + ((k4 + k5) + (k6 + k7)) + k8);
    k0 *= inv; k1 *= inv; k2 *= inv; k3 *= inv; k4 *= inv;
    k5 *= inv; k6 *= inv; k7 *= inv; k8 *= inv;

    // rolling-register conv: thread = one column, 14-row strip
    const int xc = tid & 63;             // column 0..55 (56..63 idle)
    const int g  = tid >> 6;             // row-group 0..3
    if (xc < 56) {
        const int y0 = g * 14;
        const float* base = sm + xc + 3;
        const float* r0 = base + (y0) * 64;
        const float* r1 = base + (y0 + 1) * 64;
        float a0 = r0[0], a1 = r0[1], a2 = r0[2];
        float b0 = r1[0], b1 = r1[1], b2 = r1[2];
        #pragma unroll
        for (int r = 0; r < 14; ++r) {
            const float* r2 = base + (y0 + 2 + r) * 64;
            const float c0 = r2[0], c1 = r2[1], c2 = r2[2];
            const float v = a0 * k0 + a1 * k1 + a2 * k2
                          + b0 * k3 + b1 * k4 + b2 * k5
                          + c0 * k6 + c1 * k7 + c2 * k8
                          + b1;                          // residual
            o[(y0 + r) * W_ + xc] = v;
            a0 = b0; a1 = b1; a2 = b2;
            b0 = c0; b1 = c1; b2 = c2;
        }
    }
}

// ---------------------------------------------------------------------------
extern "C" void kernel_launch(void* const* d_in, const int* in_sizes, int n_in,
                              void* d_out, int out_size, void* d_ws, size_t ws_size,
                              hipStream_t stream) {
    const float* x  = (const float*)d_in[0];
    const float* w1 = (const float*)d_in[1];
    const float* b1 = (const float*)d_in[2];
    const float* w2 = (const float*)d_in[3];
    const float* b2 = (const float*)d_in[4];
    float* out = (float*)d_out;

    float* gap   = (float*)d_ws;                 // 8192 floats
    float* hid_g = gap + BC_;                    // 32*64 = 2048 floats

    gap_kernel<<<BC_, 256, 0, stream>>>(x, gap);
    hid_kernel<<<B_, 256, 0, stream>>>(gap, w1, b1, hid_g);
    dconv_kernel<<<BC_, 256, 0, stream>>>(x, hid_g, w2, b2, out);
}